// Round 2
// 5001.651 us; speedup vs baseline: 1.0934x; 1.0934x over previous
//
#include <hip/hip_runtime.h>
#include <math.h>

#define T_SEQ 256
#define BATCH 128
#define HID 512
#define NL 4
// d_out: out [128][256][768] fp32 | hT [4][128][512] | cT [4][128][512]
#define HT_OFF 25165824u
#define CT_OFF 25427968u
// ws: h_all bf16 [4][257][128][512] | xp bf16 [256][128][512] | flags [4][256][64]
#define HALL_ELEMS 67371008u
#define XP_ELEMS   16777216u
#define FLG_OFF(l,t) ((((l) << 8) + (t)) << 6)   // 64 dwords per (l,t); counters at dwords 0,16,32,48

typedef __attribute__((ext_vector_type(8))) short bf16x8;
typedef __attribute__((ext_vector_type(4))) float f32x4;

__device__ __forceinline__ short f2bf(float f) {
    unsigned u = __float_as_uint(f);
    u = (u + 0x7fffu + ((u >> 16) & 1u)) >> 16;
    return (short)u;
}
__device__ __forceinline__ unsigned pack2(float a, float b) {
    return ((unsigned)(unsigned short)f2bf(a)) |
           (((unsigned)(unsigned short)f2bf(b)) << 16);
}
// race-exposed load: 16B fragment via two 8B agent-scope atomic loads,
// bypassing stale local caches so we read the coherence point the producers stored to.
__device__ __forceinline__ bf16x8 ld8_sc1(const short* p) {
    unsigned long long q0 = __hip_atomic_load((const unsigned long long*)p,
                                              __ATOMIC_RELAXED, __HIP_MEMORY_SCOPE_AGENT);
    unsigned long long q1 = __hip_atomic_load((const unsigned long long*)(p + 4),
                                              __ATOMIC_RELAXED, __HIP_MEMORY_SCOPE_AGENT);
    union { unsigned long long q[2]; bf16x8 v; } u;
    u.q[0] = q0; u.q[1] = q1;
    return u.v;
}
// single-wave poll of the 4 arrival counters (16 producers each) for one (l,t)
__device__ __forceinline__ void poll_cnt4(const unsigned* base, int lane) {
    const unsigned* p = base + ((lane & 3) << 4);   // 4 counters, 64B apart
    unsigned v = __hip_atomic_load(p, __ATOMIC_RELAXED, __HIP_MEMORY_SCOPE_AGENT);
    while (__any(v < 16u)) {
        __builtin_amdgcn_s_sleep(1);
        v = __hip_atomic_load(p, __ATOMIC_RELAXED, __HIP_MEMORY_SCOPE_AGENT);
    }
    asm volatile("" ::: "memory");                  // poll completes before publish
}
// sibling waves spin on a monotonic LDS progress word (acquire pairs with
// the polling wave's release publish)
__device__ __forceinline__ void lds_wait(int* p, int want) {
    while (__hip_atomic_load(p, __ATOMIC_ACQUIRE, __HIP_MEMORY_SCOPE_WORKGROUP) < want)
        __builtin_amdgcn_s_sleep(1);
    asm volatile("" ::: "memory");
}

// ---------------------------------------------------------------------------
__global__ void init_kernel(short* __restrict__ h_all, unsigned* __restrict__ flg,
                            const float* __restrict__ h0) {
    int idx = blockIdx.x * 256 + threadIdx.x;       // grid 1024*256
    if (idx < NL * BATCH * HID) {
        int l = idx >> 16, rest = idx & 65535;
        h_all[((size_t)(l * 257) << 16) + rest] = f2bf(h0[idx]);
    }
    if (idx < NL * T_SEQ * 64) flg[idx] = 0u;
}

// ---------------------------------------------------------------------------
// xp-GEMM: xp[t][b][n] (bf16) = x[b][t][:768] @ W_in[n][:768] + b_in[n]
// ---------------------------------------------------------------------------
__global__ __launch_bounds__(256) void gemm_xp(const float* __restrict__ x,
                                               const float* __restrict__ W_in,
                                               const float* __restrict__ b_in,
                                               short* __restrict__ xp) {
    __shared__ short As[128 * 72];
    __shared__ short Bs[128 * 72];
    const int tid = threadIdx.x;
    const int w = tid >> 6, lane = tid & 63;
    const int m = lane & 15, quad = lane >> 4;
    const int rowbase = blockIdx.x * 128;           // M = 32768 (b*256+t)
    const int colbase = blockIdx.y * 128;           // N = 512
    f32x4 acc[2][8];
#pragma unroll
    for (int rt = 0; rt < 2; ++rt)
#pragma unroll
        for (int ct = 0; ct < 8; ++ct) { f32x4 z = {0.f,0.f,0.f,0.f}; acc[rt][ct] = z; }

    for (int k0 = 0; k0 < 768; k0 += 64) {
        __syncthreads();
#pragma unroll
        for (int i = 0; i < 8; ++i) {
            int q = tid + (i << 8);
            int r = q >> 4, f4 = (q & 15) << 2;
            float4 v = *(const float4*)(x + (size_t)(rowbase + r) * 768 + k0 + f4);
            uint2 p; p.x = pack2(v.x, v.y); p.y = pack2(v.z, v.w);
            *(uint2*)&As[r * 72 + f4] = p;
        }
#pragma unroll
        for (int i = 0; i < 8; ++i) {
            int q = tid + (i << 8);
            int r = q >> 4, f4 = (q & 15) << 2;
            float4 v = *(const float4*)(W_in + (size_t)(colbase + r) * 768 + k0 + f4);
            uint2 p; p.x = pack2(v.x, v.y); p.y = pack2(v.z, v.w);
            *(uint2*)&Bs[r * 72 + f4] = p;
        }
        __syncthreads();
#pragma unroll
        for (int ks = 0; ks < 2; ++ks) {
            int kof = (ks << 5) + (quad << 3);
            bf16x8 a0 = *(const bf16x8*)&As[((w * 2 + 0) * 16 + m) * 72 + kof];
            bf16x8 a1 = *(const bf16x8*)&As[((w * 2 + 1) * 16 + m) * 72 + kof];
#pragma unroll
            for (int ct = 0; ct < 8; ++ct) {
                bf16x8 b = *(const bf16x8*)&Bs[(ct * 16 + m) * 72 + kof];
                acc[0][ct] = __builtin_amdgcn_mfma_f32_16x16x32_bf16(a0, b, acc[0][ct], 0, 0, 0);
                acc[1][ct] = __builtin_amdgcn_mfma_f32_16x16x32_bf16(a1, b, acc[1][ct], 0, 0, 0);
            }
        }
    }
    float bias_r[8];
#pragma unroll
    for (int ct = 0; ct < 8; ++ct) bias_r[ct] = b_in[colbase + ct * 16 + m];
#pragma unroll
    for (int rt = 0; rt < 2; ++rt)
#pragma unroll
        for (int reg = 0; reg < 4; ++reg) {
            int m_glob = rowbase + (w * 2 + rt) * 16 + quad * 4 + reg;
            int t = m_glob & 255, b = m_glob >> 8;
            short* dst = xp + (((size_t)(t << 7) + b) << 9);
#pragma unroll
            for (int ct = 0; ct < 8; ++ct)
                dst[colbase + ct * 16 + m] = f2bf(acc[rt][ct][reg] + bias_r[ct]);
        }
}

// ---------------------------------------------------------------------------
// out-GEMM: out[b][t][n] (fp32) = h3[t][b][:512] @ W_out[n][:512] + b_out[n]
// ---------------------------------------------------------------------------
__global__ __launch_bounds__(256) void gemm_out(const short* __restrict__ h3,
                                                const float* __restrict__ W_out,
                                                const float* __restrict__ b_out,
                                                float* __restrict__ out) {
    __shared__ short As[128 * 72];
    __shared__ short Bs[128 * 72];
    const int tid = threadIdx.x;
    const int w = tid >> 6, lane = tid & 63;
    const int m = lane & 15, quad = lane >> 4;
    const int rowbase = blockIdx.x * 128;           // M = 32768 (t*128+b)
    const int colbase = blockIdx.y * 128;           // N = 768
    f32x4 acc[2][8];
#pragma unroll
    for (int rt = 0; rt < 2; ++rt)
#pragma unroll
        for (int ct = 0; ct < 8; ++ct) { f32x4 z = {0.f,0.f,0.f,0.f}; acc[rt][ct] = z; }

    for (int k0 = 0; k0 < 512; k0 += 64) {
        __syncthreads();
#pragma unroll
        for (int i = 0; i < 4; ++i) {
            int q = tid + (i << 8);
            int r = q >> 3, seg = (q & 7) << 3;
            *(bf16x8*)&As[r * 72 + seg] =
                *(const bf16x8*)(h3 + (size_t)(rowbase + r) * 512 + k0 + seg);
        }
#pragma unroll
        for (int i = 0; i < 8; ++i) {
            int q = tid + (i << 8);
            int r = q >> 4, f4 = (q & 15) << 2;
            float4 v = *(const float4*)(W_out + (size_t)(colbase + r) * 512 + k0 + f4);
            uint2 p; p.x = pack2(v.x, v.y); p.y = pack2(v.z, v.w);
            *(uint2*)&Bs[r * 72 + f4] = p;
        }
        __syncthreads();
#pragma unroll
        for (int ks = 0; ks < 2; ++ks) {
            int kof = (ks << 5) + (quad << 3);
            bf16x8 a0 = *(const bf16x8*)&As[((w * 2 + 0) * 16 + m) * 72 + kof];
            bf16x8 a1 = *(const bf16x8*)&As[((w * 2 + 1) * 16 + m) * 72 + kof];
#pragma unroll
            for (int ct = 0; ct < 8; ++ct) {
                bf16x8 b = *(const bf16x8*)&Bs[(ct * 16 + m) * 72 + kof];
                acc[0][ct] = __builtin_amdgcn_mfma_f32_16x16x32_bf16(a0, b, acc[0][ct], 0, 0, 0);
                acc[1][ct] = __builtin_amdgcn_mfma_f32_16x16x32_bf16(a1, b, acc[1][ct], 0, 0, 0);
            }
        }
    }
    float bias_r[8];
#pragma unroll
    for (int ct = 0; ct < 8; ++ct) bias_r[ct] = b_out[colbase + ct * 16 + m];
#pragma unroll
    for (int rt = 0; rt < 2; ++rt)
#pragma unroll
        for (int reg = 0; reg < 4; ++reg) {
            int m_glob = rowbase + (w * 2 + rt) * 16 + quad * 4 + reg;
            int t = m_glob >> 7, b = m_glob & 127;
            float* dst = out + (size_t)b * 196608 + (size_t)t * 768;
#pragma unroll
            for (int ct = 0; ct < 8; ++ct)
                dst[colbase + ct * 16 + m] = acc[rt][ct][reg] + bias_r[ct];
        }
}

// ---------------------------------------------------------------------------
// Persistent MFMA LSTM pipeline. 256 blocks = 4 layers x 64 col-chunks,
// 512 thr = 8 waves. Waves 0-3: x-part (W_ih), waves 4-7: h-part (W_hh).
// Weights in registers. h via relaxed agent stores -> coherence point.
// Sync protocol (v2b): 4 arrival counters per (l,t) (16 producers each,
// 64B apart); ONE wave per dependency polls globally (wave 0: x-dep,
// wave 4: h-dep), siblings spin on a monotonic LDS word via a
// release/acquire handoff. x/h gate partials go to separate LDS arrays
// -> only 2 barriers per step.
// ---------------------------------------------------------------------------
__global__ __launch_bounds__(512, 2) void lstm_pipeline(
    const short* __restrict__ xp, short* __restrict__ h_all,
    unsigned* __restrict__ flg,
    const float* __restrict__ W_ih, const float* __restrict__ W_hh,
    const float* __restrict__ b_ih, const float* __restrict__ b_hh,
    const float* __restrict__ c0, float* __restrict__ d_out) {
    __shared__ float gatesX[128 * 33];
    __shared__ float gatesH[128 * 33];
    __shared__ float cL[128 * 8];
    __shared__ float biasL[32];
    __shared__ int ldsdep[2];                       // [0]: x-dep step+1, [1]: h-dep step

    const int tid = threadIdx.x;
    const int l = blockIdx.x >> 6, c = blockIdx.x & 63;
    const int w = tid >> 6, lane = tid & 63;
    const int m = lane & 15, quad = lane >> 4;
    const bool hw = (w >= 4);
    const int w2 = w & 3;

    // --- load weight fragments into registers (once) ---
    const float* Wsrc = hw ? W_hh : W_ih;
    bf16x8 wf[32];
#pragma unroll
    for (int ks = 0; ks < 16; ++ks) {
#pragma unroll
        for (int ct = 0; ct < 2; ++ct) {
            int u = ct * 16 + m;
            int gr = ((u >> 3) << 9) + (c << 3) + (u & 7);
            const float* s = Wsrc + ((size_t)(l * 2048 + gr) << 9) + ks * 32 + quad * 8;
            float4 v0 = *(const float4*)s;
            float4 v1 = *(const float4*)(s + 4);
            uint4 p;
            p.x = pack2(v0.x, v0.y); p.y = pack2(v0.z, v0.w);
            p.z = pack2(v1.x, v1.y); p.w = pack2(v1.z, v1.w);
            wf[ks * 2 + ct] = *(bf16x8*)&p;
        }
    }
    if (tid < 32) {
        int gr = ((tid >> 3) << 9) + (c << 3) + (tid & 7);
        biasL[tid] = b_ih[l * 2048 + gr] + b_hh[l * 2048 + gr];
    }
    if (tid < 2) ldsdep[tid] = 0;
    for (int p = tid; p < 1024; p += 512) {
        int r = p >> 3, hc = p & 7;
        cL[p] = c0[((size_t)l << 16) + (r << 9) + (c << 3) + hc];
    }
    __syncthreads();

    const int er = tid >> 2, eq = (tid & 3) << 1;    // elementwise: row, col-pair

    for (int t = 0; t < T_SEQ; ++t) {
        // --- dependency wait: one wave polls globally, siblings spin on LDS ---
        if (hw) {
            if (t > 0) {
                if (w == 4) {
                    poll_cnt4(flg + FLG_OFF(l, t - 1), lane);
                    __hip_atomic_store(&ldsdep[1], t, __ATOMIC_RELEASE,
                                       __HIP_MEMORY_SCOPE_WORKGROUP);
                } else {
                    lds_wait(&ldsdep[1], t);
                }
            }
        } else if (l > 0) {
            if (w == 0) {
                poll_cnt4(flg + FLG_OFF(l - 1, t), lane);
                __hip_atomic_store(&ldsdep[0], t + 1, __ATOMIC_RELEASE,
                                   __HIP_MEMORY_SCOPE_WORKGROUP);
            } else {
                lds_wait(&ldsdep[0], t + 1);
            }
        }
        asm volatile("" ::: "memory");               // keep A-loads below the wait

        f32x4 z = {0.f, 0.f, 0.f, 0.f};
        f32x4 acc00 = z, acc01 = z, acc10 = z, acc11 = z;

        if (!hw && l == 0) {
            // race-free path: xp written by a prior dispatch -> plain cached loads
            const short* src = xp + ((size_t)t << 16);
#pragma unroll
            for (int ks = 0; ks < 16; ++ks) {
                int ka = ks * 32 + quad * 8;
                bf16x8 a0 = *(const bf16x8*)(src + ((size_t)(w2 * 32 + m) << 9) + ka);
                bf16x8 a1 = *(const bf16x8*)(src + ((size_t)(w2 * 32 + 16 + m) << 9) + ka);
                acc00 = __builtin_amdgcn_mfma_f32_16x16x32_bf16(a0, wf[ks * 2 + 0], acc00, 0, 0, 0);
                acc01 = __builtin_amdgcn_mfma_f32_16x16x32_bf16(a0, wf[ks * 2 + 1], acc01, 0, 0, 0);
                acc10 = __builtin_amdgcn_mfma_f32_16x16x32_bf16(a1, wf[ks * 2 + 0], acc10, 0, 0, 0);
                acc11 = __builtin_amdgcn_mfma_f32_16x16x32_bf16(a1, wf[ks * 2 + 1], acc11, 0, 0, 0);
            }
        } else {
            // race-exposed path: h written by other blocks this dispatch -> sc1 loads
            const short* src = hw
                ? (h_all + ((size_t)(l * 257 + t) << 16))
                : (h_all + ((size_t)((l - 1) * 257 + t + 1) << 16));
#pragma unroll
            for (int ks = 0; ks < 16; ++ks) {
                int ka = ks * 32 + quad * 8;
                bf16x8 a0 = ld8_sc1(src + ((size_t)(w2 * 32 + m) << 9) + ka);
                bf16x8 a1 = ld8_sc1(src + ((size_t)(w2 * 32 + 16 + m) << 9) + ka);
                acc00 = __builtin_amdgcn_mfma_f32_16x16x32_bf16(a0, wf[ks * 2 + 0], acc00, 0, 0, 0);
                acc01 = __builtin_amdgcn_mfma_f32_16x16x32_bf16(a0, wf[ks * 2 + 1], acc01, 0, 0, 0);
                acc10 = __builtin_amdgcn_mfma_f32_16x16x32_bf16(a1, wf[ks * 2 + 0], acc10, 0, 0, 0);
                acc11 = __builtin_amdgcn_mfma_f32_16x16x32_bf16(a1, wf[ks * 2 + 1], acc11, 0, 0, 0);
            }
        }
        const int gb0 = w2 * 32 + quad * 4;
        float* gdst = hw ? gatesH : gatesX;
#pragma unroll
        for (int reg = 0; reg < 4; ++reg) {
            gdst[(gb0 + reg) * 33 + m]           = acc00[reg];
            gdst[(gb0 + reg) * 33 + 16 + m]      = acc01[reg];
            gdst[(gb0 + 16 + reg) * 33 + m]      = acc10[reg];
            gdst[(gb0 + 16 + reg) * 33 + 16 + m] = acc11[reg];
        }
        __syncthreads();                             // Bg: both partials visible

        // --- elementwise: 2 adjacent cells per thread, packed dword sc1 store ---
        float hv[2], cv[2];
#pragma unroll
        for (int e = 0; e < 2; ++e) {
            int hc = eq + e;
            float iv = gatesX[er * 33 + hc]      + gatesH[er * 33 + hc]      + biasL[hc];
            float fv = gatesX[er * 33 + 8 + hc]  + gatesH[er * 33 + 8 + hc]  + biasL[8 + hc];
            float gv = gatesX[er * 33 + 16 + hc] + gatesH[er * 33 + 16 + hc] + biasL[16 + hc];
            float ov = gatesX[er * 33 + 24 + hc] + gatesH[er * 33 + 24 + hc] + biasL[24 + hc];
            float ig = 1.f / (1.f + __expf(-iv));
            float fg = 1.f / (1.f + __expf(-fv));
            float gg = tanhf(gv);
            float og = 1.f / (1.f + __expf(-ov));
            float cn = fg * cL[er * 8 + hc] + ig * gg;
            float hn = og * tanhf(cn);
            cL[er * 8 + hc] = cn;
            hv[e] = hn; cv[e] = cn;
        }
        unsigned pk = pack2(hv[0], hv[1]);
        unsigned* hdst = (unsigned*)(h_all + ((size_t)(l * 257 + t + 1) << 16)
                                     + (er << 9) + (c << 3) + eq);
        __hip_atomic_store(hdst, pk, __ATOMIC_RELAXED, __HIP_MEMORY_SCOPE_AGENT);
        if (t == T_SEQ - 1) {
            size_t fo = ((size_t)l << 16) + (size_t)(er << 9) + (c << 3) + eq;
            d_out[HT_OFF + fo]     = hv[0];
            d_out[HT_OFF + fo + 1] = hv[1];
            d_out[CT_OFF + fo]     = cv[0];
            d_out[CT_OFF + fo + 1] = cv[1];
        }
        __syncthreads();                             // B3: drains all sc1 stores
        if (tid == 0)
            __hip_atomic_fetch_add(flg + FLG_OFF(l, t) + ((c >> 4) << 4), 1u,
                                   __ATOMIC_RELAXED, __HIP_MEMORY_SCOPE_AGENT);
    }
}

// ---------------------------------------------------------------------------
__global__ __launch_bounds__(256) void ln_kernel(float* __restrict__ out,
                                                 const float* __restrict__ g,
                                                 const float* __restrict__ bvec) {
    float* p = out + (size_t)blockIdx.x * 768;
    int tid = threadIdx.x;
    float v0 = p[tid], v1 = p[tid + 256], v2 = p[tid + 512];
    float s = v0 + v1 + v2;
    float q = v0 * v0 + v1 * v1 + v2 * v2;
    for (int off = 32; off > 0; off >>= 1) {
        s += __shfl_down(s, off);
        q += __shfl_down(q, off);
    }
    __shared__ float ss[4], qq[4];
    __shared__ float mu_s, rs_s;
    int w = tid >> 6;
    if ((tid & 63) == 0) { ss[w] = s; qq[w] = q; }
    __syncthreads();
    if (tid == 0) {
        float S = ss[0] + ss[1] + ss[2] + ss[3];
        float Q = qq[0] + qq[1] + qq[2] + qq[3];
        float mu = S * (1.f / 768.f);
        float var = Q * (1.f / 768.f) - mu * mu;
        mu_s = mu;
        rs_s = rsqrtf(var + 1e-5f);
    }
    __syncthreads();
    float mu = mu_s, rs = rs_s;
    p[tid]       = (v0 - mu) * rs * g[tid]       + bvec[tid];
    p[tid + 256] = (v1 - mu) * rs * g[tid + 256] + bvec[tid + 256];
    p[tid + 512] = (v2 - mu) * rs * g[tid + 512] + bvec[tid + 512];
}

// ---------------------------------------------------------------------------
extern "C" void kernel_launch(void* const* d_in, const int* in_sizes, int n_in,
                              void* d_out, int out_size, void* d_ws, size_t ws_size,
                              hipStream_t stream) {
    (void)in_sizes; (void)n_in; (void)out_size; (void)ws_size;
    const float* x     = (const float*)d_in[0];
    const float* h0    = (const float*)d_in[1];
    const float* c0    = (const float*)d_in[2];
    const float* W_in  = (const float*)d_in[3];
    const float* b_in  = (const float*)d_in[4];
    const float* W_ih  = (const float*)d_in[5];
    const float* W_hh  = (const float*)d_in[6];
    const float* b_ih  = (const float*)d_in[7];
    const float* b_hh  = (const float*)d_in[8];
    const float* W_out = (const float*)d_in[9];
    const float* b_out = (const float*)d_in[10];
    const float* ln_g  = (const float*)d_in[11];
    const float* ln_b  = (const float*)d_in[12];

    float* out   = (float*)d_out;
    short* h_all = (short*)d_ws;
    short* xp    = h_all + HALL_ELEMS;
    unsigned* flg = (unsigned*)(xp + XP_ELEMS);
    const short* h3 = h_all + ((size_t)(3 * 257 + 1) << 16);

    init_kernel<<<1024, 256, 0, stream>>>(h_all, flg, h0);
    gemm_xp<<<dim3(256, 4), 256, 0, stream>>>(x, W_in, b_in, xp);
    lstm_pipeline<<<256, 512, 0, stream>>>(xp, h_all, flg, W_ih, W_hh,
                                           b_ih, b_hh, c0, out);
    gemm_out<<<dim3(256, 6), 256, 0, stream>>>(h3, W_out, b_out, out);
    ln_kernel<<<32768, 256, 0, stream>>>(out, ln_g, ln_b);
}

// Round 4
// 3030.164 us; speedup vs baseline: 1.8047x; 1.6506x over previous
//
#include <hip/hip_runtime.h>
#include <math.h>

#define T_SEQ 256
#define BATCH 128
#define HID 512
#define NL 4
// d_out: out [128][256][768] fp32 | hT [4][128][512] | cT [4][128][512]
#define HT_OFF 25165824u
#define CT_OFF 25427968u
// ws: h_all bf16 [4][257][128][512] | xp bf16 [256][128][512] | flags [4][256][64]
// h_all tile layout (v4, granule-interleaved): elem (row,k) at ((k>>2)*128+row)*4+(k&3)
// xp layout: [t][b][n] row-major (also receives layer-3 h in this layout for gemm_out)
#define HALL_ELEMS 67371008u
#define XP_ELEMS   16777216u
#define FLG_OFF(l,t) ((((l) << 8) + (t)) << 6)   // 64 dwords per (l,t); counters at dwords 0,16,32,48

typedef __attribute__((ext_vector_type(8))) short bf16x8;
typedef __attribute__((ext_vector_type(4))) float f32x4;

__device__ __forceinline__ short f2bf(float f) {
    unsigned u = __float_as_uint(f);
    u = (u + 0x7fffu + ((u >> 16) & 1u)) >> 16;
    return (short)u;
}
__device__ __forceinline__ unsigned pack2(float a, float b) {
    return ((unsigned)(unsigned short)f2bf(a)) |
           (((unsigned)(unsigned short)f2bf(b)) << 16);
}
// race-exposed load: 16B fragment via two 8B agent-scope atomic loads (bypass
// stale L1/L2 -> LLC coherence point). v4 layout puts the two 8B halves in
// granules g and g+1 (512 shorts apart); 16 lanes at consecutive rows make
// each 8B load inst cover 4 fully-consumed 128B lines (ideal coalescing).
__device__ __forceinline__ bf16x8 ld8_sc1g(const short* p) {
    unsigned long long q0 = __hip_atomic_load((const unsigned long long*)p,
                                              __ATOMIC_RELAXED, __HIP_MEMORY_SCOPE_AGENT);
    unsigned long long q1 = __hip_atomic_load((const unsigned long long*)(p + 512),
                                              __ATOMIC_RELAXED, __HIP_MEMORY_SCOPE_AGENT);
    union { unsigned long long q[2]; bf16x8 v; } u;
    u.q[0] = q0; u.q[1] = q1;
    return u.v;
}
// single-wave poll of the 4 arrival counters (16 producers each) for one (l,t)
__device__ __forceinline__ void poll_cnt4(const unsigned* base, int lane) {
    const unsigned* p = base + ((lane & 3) << 4);   // 4 counters, 64B apart
    unsigned v = __hip_atomic_load(p, __ATOMIC_RELAXED, __HIP_MEMORY_SCOPE_AGENT);
    while (__any(v < 16u)) {
        __builtin_amdgcn_s_sleep(1);
        v = __hip_atomic_load(p, __ATOMIC_RELAXED, __HIP_MEMORY_SCOPE_AGENT);
    }
    asm volatile("" ::: "memory");                  // poll completes before publish
}
// sibling waves spin on a monotonic LDS progress word (acquire pairs with
// the polling wave's release publish)
__device__ __forceinline__ void lds_wait(int* p, int want) {
    while (__hip_atomic_load(p, __ATOMIC_ACQUIRE, __HIP_MEMORY_SCOPE_WORKGROUP) < want)
        __builtin_amdgcn_s_sleep(1);
    asm volatile("" ::: "memory");
}

// ---------------------------------------------------------------------------
__global__ void init_kernel(short* __restrict__ h_all, unsigned* __restrict__ flg,
                            const float* __restrict__ h0) {
    int idx = blockIdx.x * 256 + threadIdx.x;       // grid 1024*256
    if (idx < NL * BATCH * HID) {
        int l = idx >> 16, rest = idx & 65535;
        int r = rest >> 9, k = rest & 511;
        h_all[((size_t)(l * 257) << 16) + (((size_t)(k >> 2)) << 9) + (r << 2) + (k & 3)]
            = f2bf(h0[idx]);
    }
    if (idx < NL * T_SEQ * 64) flg[idx] = 0u;
}

// ---------------------------------------------------------------------------
// xp-GEMM: xp[t][b][n] (bf16) = x[b][t][:768] @ W_in[n][:768] + b_in[n]
// ---------------------------------------------------------------------------
__global__ __launch_bounds__(256) void gemm_xp(const float* __restrict__ x,
                                               const float* __restrict__ W_in,
                                               const float* __restrict__ b_in,
                                               short* __restrict__ xp) {
    __shared__ short As[128 * 72];
    __shared__ short Bs[128 * 72];
    const int tid = threadIdx.x;
    const int w = tid >> 6, lane = tid & 63;
    const int m = lane & 15, quad = lane >> 4;
    const int rowbase = blockIdx.x * 128;           // M = 32768 (b*256+t)
    const int colbase = blockIdx.y * 128;           // N = 512
    f32x4 acc[2][8];
#pragma unroll
    for (int rt = 0; rt < 2; ++rt)
#pragma unroll
        for (int ct = 0; ct < 8; ++ct) { f32x4 z = {0.f,0.f,0.f,0.f}; acc[rt][ct] = z; }

    for (int k0 = 0; k0 < 768; k0 += 64) {
        __syncthreads();
#pragma unroll
        for (int i = 0; i < 8; ++i) {
            int q = tid + (i << 8);
            int r = q >> 4, f4 = (q & 15) << 2;
            float4 v = *(const float4*)(x + (size_t)(rowbase + r) * 768 + k0 + f4);
            uint2 p; p.x = pack2(v.x, v.y); p.y = pack2(v.z, v.w);
            *(uint2*)&As[r * 72 + f4] = p;
        }
#pragma unroll
        for (int i = 0; i < 8; ++i) {
            int q = tid + (i << 8);
            int r = q >> 4, f4 = (q & 15) << 2;
            float4 v = *(const float4*)(W_in + (size_t)(colbase + r) * 768 + k0 + f4);
            uint2 p; p.x = pack2(v.x, v.y); p.y = pack2(v.z, v.w);
            *(uint2*)&Bs[r * 72 + f4] = p;
        }
        __syncthreads();
#pragma unroll
        for (int ks = 0; ks < 2; ++ks) {
            int kof = (ks << 5) + (quad << 3);
            bf16x8 a0 = *(const bf16x8*)&As[((w * 2 + 0) * 16 + m) * 72 + kof];
            bf16x8 a1 = *(const bf16x8*)&As[((w * 2 + 1) * 16 + m) * 72 + kof];
#pragma unroll
            for (int ct = 0; ct < 8; ++ct) {
                bf16x8 b = *(const bf16x8*)&Bs[(ct * 16 + m) * 72 + kof];
                acc[0][ct] = __builtin_amdgcn_mfma_f32_16x16x32_bf16(a0, b, acc[0][ct], 0, 0, 0);
                acc[1][ct] = __builtin_amdgcn_mfma_f32_16x16x32_bf16(a1, b, acc[1][ct], 0, 0, 0);
            }
        }
    }
    float bias_r[8];
#pragma unroll
    for (int ct = 0; ct < 8; ++ct) bias_r[ct] = b_in[colbase + ct * 16 + m];
#pragma unroll
    for (int rt = 0; rt < 2; ++rt)
#pragma unroll
        for (int reg = 0; reg < 4; ++reg) {
            int m_glob = rowbase + (w * 2 + rt) * 16 + quad * 4 + reg;
            int t = m_glob & 255, b = m_glob >> 8;
            short* dst = xp + (((size_t)(t << 7) + b) << 9);
#pragma unroll
            for (int ct = 0; ct < 8; ++ct)
                dst[colbase + ct * 16 + m] = f2bf(acc[rt][ct][reg] + bias_r[ct]);
        }
}

// ---------------------------------------------------------------------------
// out-GEMM: out[b][t][n] (fp32) = h3[t][b][:512] @ W_out[n][:512] + b_out[n]
// h3 comes from the xp buffer ([t][b][n] layout, dual-written by layer 3).
// ---------------------------------------------------------------------------
__global__ __launch_bounds__(256) void gemm_out(const short* __restrict__ h3,
                                                const float* __restrict__ W_out,
                                                const float* __restrict__ b_out,
                                                float* __restrict__ out) {
    __shared__ short As[128 * 72];
    __shared__ short Bs[128 * 72];
    const int tid = threadIdx.x;
    const int w = tid >> 6, lane = tid & 63;
    const int m = lane & 15, quad = lane >> 4;
    const int rowbase = blockIdx.x * 128;           // M = 32768 (t*128+b)
    const int colbase = blockIdx.y * 128;           // N = 768
    f32x4 acc[2][8];
#pragma unroll
    for (int rt = 0; rt < 2; ++rt)
#pragma unroll
        for (int ct = 0; ct < 8; ++ct) { f32x4 z = {0.f,0.f,0.f,0.f}; acc[rt][ct] = z; }

    for (int k0 = 0; k0 < 512; k0 += 64) {
        __syncthreads();
#pragma unroll
        for (int i = 0; i < 4; ++i) {
            int q = tid + (i << 8);
            int r = q >> 3, seg = (q & 7) << 3;
            *(bf16x8*)&As[r * 72 + seg] =
                *(const bf16x8*)(h3 + (size_t)(rowbase + r) * 512 + k0 + seg);
        }
#pragma unroll
        for (int i = 0; i < 8; ++i) {
            int q = tid + (i << 8);
            int r = q >> 4, f4 = (q & 15) << 2;
            float4 v = *(const float4*)(W_out + (size_t)(colbase + r) * 512 + k0 + f4);
            uint2 p; p.x = pack2(v.x, v.y); p.y = pack2(v.z, v.w);
            *(uint2*)&Bs[r * 72 + f4] = p;
        }
        __syncthreads();
#pragma unroll
        for (int ks = 0; ks < 2; ++ks) {
            int kof = (ks << 5) + (quad << 3);
            bf16x8 a0 = *(const bf16x8*)&As[((w * 2 + 0) * 16 + m) * 72 + kof];
            bf16x8 a1 = *(const bf16x8*)&As[((w * 2 + 1) * 16 + m) * 72 + kof];
#pragma unroll
            for (int ct = 0; ct < 8; ++ct) {
                bf16x8 b = *(const bf16x8*)&Bs[(ct * 16 + m) * 72 + kof];
                acc[0][ct] = __builtin_amdgcn_mfma_f32_16x16x32_bf16(a0, b, acc[0][ct], 0, 0, 0);
                acc[1][ct] = __builtin_amdgcn_mfma_f32_16x16x32_bf16(a1, b, acc[1][ct], 0, 0, 0);
            }
        }
    }
    float bias_r[8];
#pragma unroll
    for (int ct = 0; ct < 8; ++ct) bias_r[ct] = b_out[colbase + ct * 16 + m];
#pragma unroll
    for (int rt = 0; rt < 2; ++rt)
#pragma unroll
        for (int reg = 0; reg < 4; ++reg) {
            int m_glob = rowbase + (w * 2 + rt) * 16 + quad * 4 + reg;
            int t = m_glob >> 7, b = m_glob & 127;
            float* dst = out + (size_t)b * 196608 + (size_t)t * 768;
#pragma unroll
            for (int ct = 0; ct < 8; ++ct)
                dst[colbase + ct * 16 + m] = acc[rt][ct][reg] + bias_r[ct];
        }
}

// ---------------------------------------------------------------------------
// Persistent MFMA LSTM pipeline. 256 blocks = 4 layers x 64 col-chunks,
// 512 thr = 8 waves. Waves 0-3: x-part (W_ih), waves 4-7: h-part (W_hh).
// Weights in registers. h via relaxed agent stores -> coherence point (LLC).
// Sync (v2b): 4 arrival counters per (l,t), one polling wave per dep,
// release/acquire LDS handoff, split gatesX/gatesH -> 2 barriers/step.
// v4: h_all tiles use granule-interleaved layout ((k>>2)*128+row)*4+(k&3) so
// the mandatory sc1 (LLC-direct) fragment loads are line-coalesced: each 8B
// load inst = 16 consecutive rows x 8B = 4 full 128B lines (was 16 lines at
// 8B-used each -> 8x fewer LLC requests). Layer 3 dual-writes h in [t][b][n]
// layout into the xp buffer (safe: flag chain orders it after layer-0's xp
// reads) so gemm_out reads it unchanged.
// ---------------------------------------------------------------------------
__global__ __launch_bounds__(512, 2) void lstm_pipeline(
    short* __restrict__ xp, short* __restrict__ h_all,
    unsigned* __restrict__ flg,
    const float* __restrict__ W_ih, const float* __restrict__ W_hh,
    const float* __restrict__ b_ih, const float* __restrict__ b_hh,
    const float* __restrict__ c0, float* __restrict__ d_out) {
    __shared__ float gatesX[128 * 33];
    __shared__ float gatesH[128 * 33];
    __shared__ float cL[128 * 8];
    __shared__ float biasL[32];
    __shared__ int ldsdep[2];                       // [0]: x-dep step+1, [1]: h-dep step

    const int tid = threadIdx.x;
    const int l = blockIdx.x >> 6, c = blockIdx.x & 63;
    const int w = tid >> 6, lane = tid & 63;
    const int m = lane & 15, quad = lane >> 4;
    const bool hw = (w >= 4);
    const int w2 = w & 3;

    // --- load weight fragments into registers (once) ---
    const float* Wsrc = hw ? W_hh : W_ih;
    bf16x8 wf[32];
#pragma unroll
    for (int ks = 0; ks < 16; ++ks) {
#pragma unroll
        for (int ct = 0; ct < 2; ++ct) {
            int u = ct * 16 + m;
            int gr = ((u >> 3) << 9) + (c << 3) + (u & 7);
            const float* s = Wsrc + ((size_t)(l * 2048 + gr) << 9) + ks * 32 + quad * 8;
            float4 v0 = *(const float4*)s;
            float4 v1 = *(const float4*)(s + 4);
            uint4 p;
            p.x = pack2(v0.x, v0.y); p.y = pack2(v0.z, v0.w);
            p.z = pack2(v1.x, v1.y); p.w = pack2(v1.z, v1.w);
            wf[ks * 2 + ct] = *(bf16x8*)&p;
        }
    }
    if (tid < 32) {
        int gr = ((tid >> 3) << 9) + (c << 3) + (tid & 7);
        biasL[tid] = b_ih[l * 2048 + gr] + b_hh[l * 2048 + gr];
    }
    if (tid < 2) ldsdep[tid] = 0;
    for (int p = tid; p < 1024; p += 512) {
        int r = p >> 3, hc = p & 7;
        cL[p] = c0[((size_t)l << 16) + (r << 9) + (c << 3) + hc];
    }
    __syncthreads();

    const int er = tid >> 2, eq = (tid & 3) << 1;    // elementwise: row, col-pair

    for (int t = 0; t < T_SEQ; ++t) {
        // --- dependency wait: one wave polls globally, siblings spin on LDS ---
        if (hw) {
            if (t > 0) {
                if (w == 4) {
                    poll_cnt4(flg + FLG_OFF(l, t - 1), lane);
                    __hip_atomic_store(&ldsdep[1], t, __ATOMIC_RELEASE,
                                       __HIP_MEMORY_SCOPE_WORKGROUP);
                } else {
                    lds_wait(&ldsdep[1], t);
                }
            }
        } else if (l > 0) {
            if (w == 0) {
                poll_cnt4(flg + FLG_OFF(l - 1, t), lane);
                __hip_atomic_store(&ldsdep[0], t + 1, __ATOMIC_RELEASE,
                                   __HIP_MEMORY_SCOPE_WORKGROUP);
            } else {
                lds_wait(&ldsdep[0], t + 1);
            }
        }
        asm volatile("" ::: "memory");               // keep A-loads below the wait

        f32x4 z = {0.f, 0.f, 0.f, 0.f};
        f32x4 acc00 = z, acc01 = z, acc10 = z, acc11 = z;

        if (!hw && l == 0) {
            // race-free path: xp written by a prior dispatch -> plain cached loads
            const short* src = xp + ((size_t)t << 16);
#pragma unroll
            for (int ks = 0; ks < 16; ++ks) {
                int ka = ks * 32 + quad * 8;
                bf16x8 a0 = *(const bf16x8*)(src + ((size_t)(w2 * 32 + m) << 9) + ka);
                bf16x8 a1 = *(const bf16x8*)(src + ((size_t)(w2 * 32 + 16 + m) << 9) + ka);
                acc00 = __builtin_amdgcn_mfma_f32_16x16x32_bf16(a0, wf[ks * 2 + 0], acc00, 0, 0, 0);
                acc01 = __builtin_amdgcn_mfma_f32_16x16x32_bf16(a0, wf[ks * 2 + 1], acc01, 0, 0, 0);
                acc10 = __builtin_amdgcn_mfma_f32_16x16x32_bf16(a1, wf[ks * 2 + 0], acc10, 0, 0, 0);
                acc11 = __builtin_amdgcn_mfma_f32_16x16x32_bf16(a1, wf[ks * 2 + 1], acc11, 0, 0, 0);
            }
        } else {
            // race-exposed path: h written by other blocks this dispatch -> sc1 loads
            // v4 layout: fragment (row, k..k+7) = 8B at ((k>>2)<<9)+(row<<2) and +512
            const short* src = hw
                ? (h_all + ((size_t)(l * 257 + t) << 16))
                : (h_all + ((size_t)((l - 1) * 257 + t + 1) << 16));
#pragma unroll
            for (int ks = 0; ks < 16; ++ks) {
                int g = ks * 8 + quad * 2;           // granule index of k = ks*32+quad*8
                const short* p = src + ((size_t)g << 9) + ((w2 * 32 + m) << 2);
                bf16x8 a0 = ld8_sc1g(p);
                bf16x8 a1 = ld8_sc1g(p + 64);        // rows +16
                acc00 = __builtin_amdgcn_mfma_f32_16x16x32_bf16(a0, wf[ks * 2 + 0], acc00, 0, 0, 0);
                acc01 = __builtin_amdgcn_mfma_f32_16x16x32_bf16(a0, wf[ks * 2 + 1], acc01, 0, 0, 0);
                acc10 = __builtin_amdgcn_mfma_f32_16x16x32_bf16(a1, wf[ks * 2 + 0], acc10, 0, 0, 0);
                acc11 = __builtin_amdgcn_mfma_f32_16x16x32_bf16(a1, wf[ks * 2 + 1], acc11, 0, 0, 0);
            }
        }
        const int gb0 = w2 * 32 + quad * 4;
        float* gdst = hw ? gatesH : gatesX;
#pragma unroll
        for (int reg = 0; reg < 4; ++reg) {
            gdst[(gb0 + reg) * 33 + m]           = acc00[reg];
            gdst[(gb0 + reg) * 33 + 16 + m]      = acc01[reg];
            gdst[(gb0 + 16 + reg) * 33 + m]      = acc10[reg];
            gdst[(gb0 + 16 + reg) * 33 + 16 + m] = acc11[reg];
        }
        __syncthreads();                             // Bg: both partials visible

        // --- elementwise: 2 adjacent cells per thread, packed dword sc1 store ---
        float hv[2], cv[2];
#pragma unroll
        for (int e = 0; e < 2; ++e) {
            int hc = eq + e;
            float iv = gatesX[er * 33 + hc]      + gatesH[er * 33 + hc]      + biasL[hc];
            float fv = gatesX[er * 33 + 8 + hc]  + gatesH[er * 33 + 8 + hc]  + biasL[8 + hc];
            float gv = gatesX[er * 33 + 16 + hc] + gatesH[er * 33 + 16 + hc] + biasL[16 + hc];
            float ov = gatesX[er * 33 + 24 + hc] + gatesH[er * 33 + 24 + hc] + biasL[24 + hc];
            float ig = 1.f / (1.f + __expf(-iv));
            float fg = 1.f / (1.f + __expf(-fv));
            float gg = tanhf(gv);
            float og = 1.f / (1.f + __expf(-ov));
            float cn = fg * cL[er * 8 + hc] + ig * gg;
            float hn = og * tanhf(cn);
            cL[er * 8 + hc] = cn;
            hv[e] = hn; cv[e] = cn;
        }
        unsigned pk = pack2(hv[0], hv[1]);
        // v4 layout store: k = c*8+eq -> granule c*2+(eq>>2), dword at (g<<9)+(er<<2)+(eq&3)
        {
            int g = c * 2 + (eq >> 2);
            unsigned* hdst = (unsigned*)(h_all + ((size_t)(l * 257 + t + 1) << 16)
                                         + ((size_t)g << 9) + (er << 2) + (eq & 3));
            __hip_atomic_store(hdst, pk, __ATOMIC_RELAXED, __HIP_MEMORY_SCOPE_AGENT);
        }
        if (l == 3) {
            // dual-write old [t][b][n] layout into xp for gemm_out (ordered after
            // layer-0's xp[t] reads via the flag chain)
            unsigned* xdst = (unsigned*)(xp + ((size_t)t << 16) + (er << 9) + (c << 3) + eq);
            __hip_atomic_store(xdst, pk, __ATOMIC_RELAXED, __HIP_MEMORY_SCOPE_AGENT);
        }
        if (t == T_SEQ - 1) {
            size_t fo = ((size_t)l << 16) + (size_t)(er << 9) + (c << 3) + eq;
            d_out[HT_OFF + fo]     = hv[0];
            d_out[HT_OFF + fo + 1] = hv[1];
            d_out[CT_OFF + fo]     = cv[0];
            d_out[CT_OFF + fo + 1] = cv[1];
        }
        __syncthreads();                             // B3: drains all sc1 stores
        if (tid == 0)
            __hip_atomic_fetch_add(flg + FLG_OFF(l, t) + ((c >> 4) << 4), 1u,
                                   __ATOMIC_RELAXED, __HIP_MEMORY_SCOPE_AGENT);
    }
}

// ---------------------------------------------------------------------------
__global__ __launch_bounds__(256) void ln_kernel(float* __restrict__ out,
                                                 const float* __restrict__ g,
                                                 const float* __restrict__ bvec) {
    float* p = out + (size_t)blockIdx.x * 768;
    int tid = threadIdx.x;
    float v0 = p[tid], v1 = p[tid + 256], v2 = p[tid + 512];
    float s = v0 + v1 + v2;
    float q = v0 * v0 + v1 * v1 + v2 * v2;
    for (int off = 32; off > 0; off >>= 1) {
        s += __shfl_down(s, off);
        q += __shfl_down(q, off);
    }
    __shared__ float ss[4], qq[4];
    __shared__ float mu_s, rs_s;
    int w = tid >> 6;
    if ((tid & 63) == 0) { ss[w] = s; qq[w] = q; }
    __syncthreads();
    if (tid == 0) {
        float S = ss[0] + ss[1] + ss[2] + ss[3];
        float Q = qq[0] + qq[1] + qq[2] + qq[3];
        float mu = S * (1.f / 768.f);
        float var = Q * (1.f / 768.f) - mu * mu;
        mu_s = mu;
        rs_s = rsqrtf(var + 1e-5f);
    }
    __syncthreads();
    float mu = mu_s, rs = rs_s;
    p[tid]       = (v0 - mu) * rs * g[tid]       + bvec[tid];
    p[tid + 256] = (v1 - mu) * rs * g[tid + 256] + bvec[tid + 256];
    p[tid + 512] = (v2 - mu) * rs * g[tid + 512] + bvec[tid + 512];
}

// ---------------------------------------------------------------------------
extern "C" void kernel_launch(void* const* d_in, const int* in_sizes, int n_in,
                              void* d_out, int out_size, void* d_ws, size_t ws_size,
                              hipStream_t stream) {
    (void)in_sizes; (void)n_in; (void)out_size; (void)ws_size;
    const float* x     = (const float*)d_in[0];
    const float* h0    = (const float*)d_in[1];
    const float* c0    = (const float*)d_in[2];
    const float* W_in  = (const float*)d_in[3];
    const float* b_in  = (const float*)d_in[4];
    const float* W_ih  = (const float*)d_in[5];
    const float* W_hh  = (const float*)d_in[6];
    const float* b_ih  = (const float*)d_in[7];
    const float* b_hh  = (const float*)d_in[8];
    const float* W_out = (const float*)d_in[9];
    const float* b_out = (const float*)d_in[10];
    const float* ln_g  = (const float*)d_in[11];
    const float* ln_b  = (const float*)d_in[12];

    float* out   = (float*)d_out;
    short* h_all = (short*)d_ws;
    short* xp    = h_all + HALL_ELEMS;
    unsigned* flg = (unsigned*)(xp + XP_ELEMS);

    init_kernel<<<1024, 256, 0, stream>>>(h_all, flg, h0);
    gemm_xp<<<dim3(256, 4), 256, 0, stream>>>(x, W_in, b_in, xp);
    lstm_pipeline<<<256, 512, 0, stream>>>(xp, h_all, flg, W_ih, W_hh,
                                           b_ih, b_hh, c0, out);
    gemm_out<<<dim3(256, 6), 256, 0, stream>>>(xp, W_out, b_out, out);
    ln_kernel<<<32768, 256, 0, stream>>>(out, ln_g, ln_b);
}

// Round 5
// 2894.320 us; speedup vs baseline: 1.8894x; 1.0469x over previous
//
#include <hip/hip_runtime.h>
#include <math.h>

#define T_SEQ 256
#define BATCH 128
#define HID 512
#define NL 4
// d_out: out [128][256][768] fp32 | hT [4][128][512] | cT [4][128][512]
#define HT_OFF 25165824u
#define CT_OFF 25427968u
// ws: h_all bf16 [4][257][128][512] | xp bf16 [256][128][512] | flags [4][256][64]
// h_all tile layout (v4, granule-interleaved): elem (row,k) at ((k>>2)*128+row)*4+(k&3)
// xp layout: [t][b][n] row-major (also receives layer-3 h in this layout for gemm_out)
#define HALL_ELEMS 67371008u
#define XP_ELEMS   16777216u
#define FLG_OFF(l,t) ((((l) << 8) + (t)) << 6)   // 64 dwords per (l,t); counters at dwords 0,16,32,48

typedef __attribute__((ext_vector_type(8))) short bf16x8;
typedef __attribute__((ext_vector_type(4))) float f32x4;

#define GSTR 35                                   // gates LDS row stride (bank-spread)

__device__ __forceinline__ short f2bf(float f) {
    unsigned u = __float_as_uint(f);
    u = (u + 0x7fffu + ((u >> 16) & 1u)) >> 16;
    return (short)u;
}
__device__ __forceinline__ unsigned pack2(float a, float b) {
    return ((unsigned)(unsigned short)f2bf(a)) |
           (((unsigned)(unsigned short)f2bf(b)) << 16);
}
// race-exposed load: 16B fragment via two 8B agent-scope atomic loads (bypass
// stale L1/L2 -> LLC coherence point). v4 layout puts the two 8B halves in
// granules g and g+1 (512 shorts apart); 16 lanes at consecutive rows make
// each 8B load inst cover 4 fully-consumed 128B lines (ideal coalescing).
__device__ __forceinline__ bf16x8 ld8_sc1g(const short* p) {
    unsigned long long q0 = __hip_atomic_load((const unsigned long long*)p,
                                              __ATOMIC_RELAXED, __HIP_MEMORY_SCOPE_AGENT);
    unsigned long long q1 = __hip_atomic_load((const unsigned long long*)(p + 512),
                                              __ATOMIC_RELAXED, __HIP_MEMORY_SCOPE_AGENT);
    union { unsigned long long q[2]; bf16x8 v; } u;
    u.q[0] = q0; u.q[1] = q1;
    return u.v;
}
// single-wave poll of the 4 arrival counters (16 producers each) for one (l,t)
__device__ __forceinline__ void poll_cnt4(const unsigned* base, int lane) {
    const unsigned* p = base + ((lane & 3) << 4);   // 4 counters, 64B apart
    unsigned v = __hip_atomic_load(p, __ATOMIC_RELAXED, __HIP_MEMORY_SCOPE_AGENT);
    while (__any(v < 16u)) {
        __builtin_amdgcn_s_sleep(1);
        v = __hip_atomic_load(p, __ATOMIC_RELAXED, __HIP_MEMORY_SCOPE_AGENT);
    }
    asm volatile("" ::: "memory");                  // poll completes before publish
}
// sibling waves spin on a monotonic LDS progress word (acquire pairs with
// the polling wave's release publish)
__device__ __forceinline__ void lds_wait(int* p, int want) {
    while (__hip_atomic_load(p, __ATOMIC_ACQUIRE, __HIP_MEMORY_SCOPE_WORKGROUP) < want)
        __builtin_amdgcn_s_sleep(1);
    asm volatile("" ::: "memory");
}
// stable tanh via exp (no libm call, no overflow): tanh(x)=sign(x)*(1-t)/(1+t), t=e^{-2|x|}
__device__ __forceinline__ float tanh_fast(float x) {
    float t = __expf(-2.f * fabsf(x));
    return copysignf((1.f - t) / (1.f + t), x);
}

// ---------------------------------------------------------------------------
__global__ void init_kernel(short* __restrict__ h_all, unsigned* __restrict__ flg,
                            const float* __restrict__ h0) {
    int idx = blockIdx.x * 256 + threadIdx.x;       // grid 1024*256
    if (idx < NL * BATCH * HID) {
        int l = idx >> 16, rest = idx & 65535;
        int r = rest >> 9, k = rest & 511;
        h_all[((size_t)(l * 257) << 16) + (((size_t)(k >> 2)) << 9) + (r << 2) + (k & 3)]
            = f2bf(h0[idx]);
    }
    if (idx < NL * T_SEQ * 64) flg[idx] = 0u;
}

// ---------------------------------------------------------------------------
// xp-GEMM: xp[t][b][n] (bf16) = x[b][t][:768] @ W_in[n][:768] + b_in[n]
// ---------------------------------------------------------------------------
__global__ __launch_bounds__(256) void gemm_xp(const float* __restrict__ x,
                                               const float* __restrict__ W_in,
                                               const float* __restrict__ b_in,
                                               short* __restrict__ xp) {
    __shared__ short As[128 * 72];
    __shared__ short Bs[128 * 72];
    const int tid = threadIdx.x;
    const int w = tid >> 6, lane = tid & 63;
    const int m = lane & 15, quad = lane >> 4;
    const int rowbase = blockIdx.x * 128;           // M = 32768 (b*256+t)
    const int colbase = blockIdx.y * 128;           // N = 512
    f32x4 acc[2][8];
#pragma unroll
    for (int rt = 0; rt < 2; ++rt)
#pragma unroll
        for (int ct = 0; ct < 8; ++ct) { f32x4 z = {0.f,0.f,0.f,0.f}; acc[rt][ct] = z; }

    for (int k0 = 0; k0 < 768; k0 += 64) {
        __syncthreads();
#pragma unroll
        for (int i = 0; i < 8; ++i) {
            int q = tid + (i << 8);
            int r = q >> 4, f4 = (q & 15) << 2;
            float4 v = *(const float4*)(x + (size_t)(rowbase + r) * 768 + k0 + f4);
            uint2 p; p.x = pack2(v.x, v.y); p.y = pack2(v.z, v.w);
            *(uint2*)&As[r * 72 + f4] = p;
        }
#pragma unroll
        for (int i = 0; i < 8; ++i) {
            int q = tid + (i << 8);
            int r = q >> 4, f4 = (q & 15) << 2;
            float4 v = *(const float4*)(W_in + (size_t)(colbase + r) * 768 + k0 + f4);
            uint2 p; p.x = pack2(v.x, v.y); p.y = pack2(v.z, v.w);
            *(uint2*)&Bs[r * 72 + f4] = p;
        }
        __syncthreads();
#pragma unroll
        for (int ks = 0; ks < 2; ++ks) {
            int kof = (ks << 5) + (quad << 3);
            bf16x8 a0 = *(const bf16x8*)&As[((w * 2 + 0) * 16 + m) * 72 + kof];
            bf16x8 a1 = *(const bf16x8*)&As[((w * 2 + 1) * 16 + m) * 72 + kof];
#pragma unroll
            for (int ct = 0; ct < 8; ++ct) {
                bf16x8 b = *(const bf16x8*)&Bs[(ct * 16 + m) * 72 + kof];
                acc[0][ct] = __builtin_amdgcn_mfma_f32_16x16x32_bf16(a0, b, acc[0][ct], 0, 0, 0);
                acc[1][ct] = __builtin_amdgcn_mfma_f32_16x16x32_bf16(a1, b, acc[1][ct], 0, 0, 0);
            }
        }
    }
    float bias_r[8];
#pragma unroll
    for (int ct = 0; ct < 8; ++ct) bias_r[ct] = b_in[colbase + ct * 16 + m];
#pragma unroll
    for (int rt = 0; rt < 2; ++rt)
#pragma unroll
        for (int reg = 0; reg < 4; ++reg) {
            int m_glob = rowbase + (w * 2 + rt) * 16 + quad * 4 + reg;
            int t = m_glob & 255, b = m_glob >> 8;
            short* dst = xp + (((size_t)(t << 7) + b) << 9);
#pragma unroll
            for (int ct = 0; ct < 8; ++ct)
                dst[colbase + ct * 16 + m] = f2bf(acc[rt][ct][reg] + bias_r[ct]);
        }
}

// ---------------------------------------------------------------------------
// out-GEMM: out[b][t][n] (fp32) = h3[t][b][:512] @ W_out[n][:512] + b_out[n]
// h3 comes from the xp buffer ([t][b][n] layout, dual-written by layer 3).
// ---------------------------------------------------------------------------
__global__ __launch_bounds__(256) void gemm_out(const short* __restrict__ h3,
                                                const float* __restrict__ W_out,
                                                const float* __restrict__ b_out,
                                                float* __restrict__ out) {
    __shared__ short As[128 * 72];
    __shared__ short Bs[128 * 72];
    const int tid = threadIdx.x;
    const int w = tid >> 6, lane = tid & 63;
    const int m = lane & 15, quad = lane >> 4;
    const int rowbase = blockIdx.x * 128;           // M = 32768 (t*128+b)
    const int colbase = blockIdx.y * 128;           // N = 768
    f32x4 acc[2][8];
#pragma unroll
    for (int rt = 0; rt < 2; ++rt)
#pragma unroll
        for (int ct = 0; ct < 8; ++ct) { f32x4 z = {0.f,0.f,0.f,0.f}; acc[rt][ct] = z; }

    for (int k0 = 0; k0 < 512; k0 += 64) {
        __syncthreads();
#pragma unroll
        for (int i = 0; i < 4; ++i) {
            int q = tid + (i << 8);
            int r = q >> 3, seg = (q & 7) << 3;
            *(bf16x8*)&As[r * 72 + seg] =
                *(const bf16x8*)(h3 + (size_t)(rowbase + r) * 512 + k0 + seg);
        }
#pragma unroll
        for (int i = 0; i < 8; ++i) {
            int q = tid + (i << 8);
            int r = q >> 4, f4 = (q & 15) << 2;
            float4 v = *(const float4*)(W_out + (size_t)(colbase + r) * 512 + k0 + f4);
            uint2 p; p.x = pack2(v.x, v.y); p.y = pack2(v.z, v.w);
            *(uint2*)&Bs[r * 72 + f4] = p;
        }
        __syncthreads();
#pragma unroll
        for (int ks = 0; ks < 2; ++ks) {
            int kof = (ks << 5) + (quad << 3);
            bf16x8 a0 = *(const bf16x8*)&As[((w * 2 + 0) * 16 + m) * 72 + kof];
            bf16x8 a1 = *(const bf16x8*)&As[((w * 2 + 1) * 16 + m) * 72 + kof];
#pragma unroll
            for (int ct = 0; ct < 8; ++ct) {
                bf16x8 b = *(const bf16x8*)&Bs[(ct * 16 + m) * 72 + kof];
                acc[0][ct] = __builtin_amdgcn_mfma_f32_16x16x32_bf16(a0, b, acc[0][ct], 0, 0, 0);
                acc[1][ct] = __builtin_amdgcn_mfma_f32_16x16x32_bf16(a1, b, acc[1][ct], 0, 0, 0);
            }
        }
    }
    float bias_r[8];
#pragma unroll
    for (int ct = 0; ct < 8; ++ct) bias_r[ct] = b_out[colbase + ct * 16 + m];
#pragma unroll
    for (int rt = 0; rt < 2; ++rt)
#pragma unroll
        for (int reg = 0; reg < 4; ++reg) {
            int m_glob = rowbase + (w * 2 + rt) * 16 + quad * 4 + reg;
            int t = m_glob >> 7, b = m_glob & 127;
            float* dst = out + (size_t)b * 196608 + (size_t)t * 768;
#pragma unroll
            for (int ct = 0; ct < 8; ++ct)
                dst[colbase + ct * 16 + m] = acc[rt][ct][reg] + bias_r[ct];
        }
}

// ---------------------------------------------------------------------------
// Persistent MFMA LSTM pipeline. 256 blocks = 4 layers x 64 col-chunks,
// 512 thr = 8 waves. Waves 0-3: x-part (W_ih), waves 4-7: h-part (W_hh).
// Weights in registers. h via relaxed agent stores -> coherence point (LLC).
// Sync (v2b): 4 arrival counters per (l,t), one polling wave per dep,
// release/acquire LDS handoff, split gatesX/gatesH -> 2 barriers/step.
// v4: granule-interleaved h layout -> line-coalesced sc1 loads.
// v5: (a) cL stride 9 (was 8: 16-way bank conflict, ~1000 cyc/beat),
//     gates stride 35 (store conflicts 4->2-way); (b) 2-deep quarter-batch
//     software pipeline on the sc1 load path (4 k-steps = 32 VGPRs in
//     flight ahead of compute; launch_bounds(512,1) lifts the 128-VGPR cap
//     so the frags stay in registers); (c) libm tanhf -> exp-based form.
// ---------------------------------------------------------------------------
#define LOADQ(A0_, A1_, kb_)                                                  \
    _Pragma("unroll")                                                         \
    for (int kk = 0; kk < 4; ++kk) {                                          \
        int ks = (kb_) * 4 + kk;                                              \
        int g = ks * 8 + quad * 2;                                            \
        const short* pq = src + ((size_t)g << 9) + ((w2 * 32 + m) << 2);      \
        A0_[kk] = ld8_sc1g(pq);                                               \
        A1_[kk] = ld8_sc1g(pq + 64);                                          \
    }
#define COMPQ(A0_, A1_, kb_)                                                  \
    _Pragma("unroll")                                                         \
    for (int kk = 0; kk < 4; ++kk) {                                          \
        int ks = (kb_) * 4 + kk;                                              \
        acc00 = __builtin_amdgcn_mfma_f32_16x16x32_bf16(A0_[kk], wf[ks*2+0], acc00, 0, 0, 0); \
        acc01 = __builtin_amdgcn_mfma_f32_16x16x32_bf16(A0_[kk], wf[ks*2+1], acc01, 0, 0, 0); \
        acc10 = __builtin_amdgcn_mfma_f32_16x16x32_bf16(A1_[kk], wf[ks*2+0], acc10, 0, 0, 0); \
        acc11 = __builtin_amdgcn_mfma_f32_16x16x32_bf16(A1_[kk], wf[ks*2+1], acc11, 0, 0, 0); \
    }

__global__ __launch_bounds__(512, 1) void lstm_pipeline(
    short* __restrict__ xp, short* __restrict__ h_all,
    unsigned* __restrict__ flg,
    const float* __restrict__ W_ih, const float* __restrict__ W_hh,
    const float* __restrict__ b_ih, const float* __restrict__ b_hh,
    const float* __restrict__ c0, float* __restrict__ d_out) {
    __shared__ float gatesX[128 * GSTR];
    __shared__ float gatesH[128 * GSTR];
    __shared__ float cL[128 * 9];
    __shared__ float biasL[32];
    __shared__ int ldsdep[2];                       // [0]: x-dep step+1, [1]: h-dep step

    const int tid = threadIdx.x;
    const int l = blockIdx.x >> 6, c = blockIdx.x & 63;
    const int w = tid >> 6, lane = tid & 63;
    const int m = lane & 15, quad = lane >> 4;
    const bool hw = (w >= 4);
    const int w2 = w & 3;

    // --- load weight fragments into registers (once) ---
    const float* Wsrc = hw ? W_hh : W_ih;
    bf16x8 wf[32];
#pragma unroll
    for (int ks = 0; ks < 16; ++ks) {
#pragma unroll
        for (int ct = 0; ct < 2; ++ct) {
            int u = ct * 16 + m;
            int gr = ((u >> 3) << 9) + (c << 3) + (u & 7);
            const float* s = Wsrc + ((size_t)(l * 2048 + gr) << 9) + ks * 32 + quad * 8;
            float4 v0 = *(const float4*)s;
            float4 v1 = *(const float4*)(s + 4);
            uint4 p;
            p.x = pack2(v0.x, v0.y); p.y = pack2(v0.z, v0.w);
            p.z = pack2(v1.x, v1.y); p.w = pack2(v1.z, v1.w);
            wf[ks * 2 + ct] = *(bf16x8*)&p;
        }
    }
    if (tid < 32) {
        int gr = ((tid >> 3) << 9) + (c << 3) + (tid & 7);
        biasL[tid] = b_ih[l * 2048 + gr] + b_hh[l * 2048 + gr];
    }
    if (tid < 2) ldsdep[tid] = 0;
    for (int p = tid; p < 1024; p += 512) {
        int r = p >> 3, hc = p & 7;
        cL[r * 9 + hc] = c0[((size_t)l << 16) + (r << 9) + (c << 3) + hc];
    }
    __syncthreads();

    const int er = tid >> 2, eq = (tid & 3) << 1;    // elementwise: row, col-pair

    for (int t = 0; t < T_SEQ; ++t) {
        // --- dependency wait: one wave polls globally, siblings spin on LDS ---
        if (hw) {
            if (t > 0) {
                if (w == 4) {
                    poll_cnt4(flg + FLG_OFF(l, t - 1), lane);
                    __hip_atomic_store(&ldsdep[1], t, __ATOMIC_RELEASE,
                                       __HIP_MEMORY_SCOPE_WORKGROUP);
                } else {
                    lds_wait(&ldsdep[1], t);
                }
            }
        } else if (l > 0) {
            if (w == 0) {
                poll_cnt4(flg + FLG_OFF(l - 1, t), lane);
                __hip_atomic_store(&ldsdep[0], t + 1, __ATOMIC_RELEASE,
                                   __HIP_MEMORY_SCOPE_WORKGROUP);
            } else {
                lds_wait(&ldsdep[0], t + 1);
            }
        }
        asm volatile("" ::: "memory");               // keep A-loads below the wait

        f32x4 z = {0.f, 0.f, 0.f, 0.f};
        f32x4 acc00 = z, acc01 = z, acc10 = z, acc11 = z;

        if (!hw && l == 0) {
            // race-free path: xp written by a prior dispatch -> plain cached loads
            const short* src = xp + ((size_t)t << 16);
#pragma unroll
            for (int ks = 0; ks < 16; ++ks) {
                int ka = ks * 32 + quad * 8;
                bf16x8 a0 = *(const bf16x8*)(src + ((size_t)(w2 * 32 + m) << 9) + ka);
                bf16x8 a1 = *(const bf16x8*)(src + ((size_t)(w2 * 32 + 16 + m) << 9) + ka);
                acc00 = __builtin_amdgcn_mfma_f32_16x16x32_bf16(a0, wf[ks * 2 + 0], acc00, 0, 0, 0);
                acc01 = __builtin_amdgcn_mfma_f32_16x16x32_bf16(a0, wf[ks * 2 + 1], acc01, 0, 0, 0);
                acc10 = __builtin_amdgcn_mfma_f32_16x16x32_bf16(a1, wf[ks * 2 + 0], acc10, 0, 0, 0);
                acc11 = __builtin_amdgcn_mfma_f32_16x16x32_bf16(a1, wf[ks * 2 + 1], acc11, 0, 0, 0);
            }
        } else {
            // race-exposed path: h written by other blocks this dispatch -> sc1 loads
            // v4 layout; v5: 2-deep quarter-batch pipeline (load 4 ks ahead)
            const short* src = hw
                ? (h_all + ((size_t)(l * 257 + t) << 16))
                : (h_all + ((size_t)((l - 1) * 257 + t + 1) << 16));
            bf16x8 Pa[4], Pb[4], Qa[4], Qb[4];
            LOADQ(Pa, Pb, 0)
            LOADQ(Qa, Qb, 1)
            COMPQ(Pa, Pb, 0)
            LOADQ(Pa, Pb, 2)
            COMPQ(Qa, Qb, 1)
            LOADQ(Qa, Qb, 3)
            COMPQ(Pa, Pb, 2)
            COMPQ(Qa, Qb, 3)
        }
        const int gb0 = w2 * 32 + quad * 4;
        float* gdst = hw ? gatesH : gatesX;
#pragma unroll
        for (int reg = 0; reg < 4; ++reg) {
            gdst[(gb0 + reg) * GSTR + m]           = acc00[reg];
            gdst[(gb0 + reg) * GSTR + 16 + m]      = acc01[reg];
            gdst[(gb0 + 16 + reg) * GSTR + m]      = acc10[reg];
            gdst[(gb0 + 16 + reg) * GSTR + 16 + m] = acc11[reg];
        }
        __syncthreads();                             // Bg: both partials visible

        // --- elementwise: 2 adjacent cells per thread, packed dword sc1 store ---
        float hv[2], cv[2];
#pragma unroll
        for (int e = 0; e < 2; ++e) {
            int hc = eq + e;
            float iv = gatesX[er * GSTR + hc]      + gatesH[er * GSTR + hc]      + biasL[hc];
            float fv = gatesX[er * GSTR + 8 + hc]  + gatesH[er * GSTR + 8 + hc]  + biasL[8 + hc];
            float gv = gatesX[er * GSTR + 16 + hc] + gatesH[er * GSTR + 16 + hc] + biasL[16 + hc];
            float ov = gatesX[er * GSTR + 24 + hc] + gatesH[er * GSTR + 24 + hc] + biasL[24 + hc];
            float ig = 1.f / (1.f + __expf(-iv));
            float fg = 1.f / (1.f + __expf(-fv));
            float gg = tanh_fast(gv);
            float og = 1.f / (1.f + __expf(-ov));
            float cn = fg * cL[er * 9 + hc] + ig * gg;
            float hn = og * tanh_fast(cn);
            cL[er * 9 + hc] = cn;
            hv[e] = hn; cv[e] = cn;
        }
        unsigned pk = pack2(hv[0], hv[1]);
        // v4 layout store: k = c*8+eq -> granule c*2+(eq>>2), dword at (g<<9)+(er<<2)+(eq&3)
        {
            int g = c * 2 + (eq >> 2);
            unsigned* hdst = (unsigned*)(h_all + ((size_t)(l * 257 + t + 1) << 16)
                                         + ((size_t)g << 9) + (er << 2) + (eq & 3));
            __hip_atomic_store(hdst, pk, __ATOMIC_RELAXED, __HIP_MEMORY_SCOPE_AGENT);
        }
        if (l == 3) {
            // dual-write old [t][b][n] layout into xp for gemm_out (ordered after
            // layer-0's xp[t] reads via the flag chain)
            unsigned* xdst = (unsigned*)(xp + ((size_t)t << 16) + (er << 9) + (c << 3) + eq);
            __hip_atomic_store(xdst, pk, __ATOMIC_RELAXED, __HIP_MEMORY_SCOPE_AGENT);
        }
        if (t == T_SEQ - 1) {
            size_t fo = ((size_t)l << 16) + (size_t)(er << 9) + (c << 3) + eq;
            d_out[HT_OFF + fo]     = hv[0];
            d_out[HT_OFF + fo + 1] = hv[1];
            d_out[CT_OFF + fo]     = cv[0];
            d_out[CT_OFF + fo + 1] = cv[1];
        }
        __syncthreads();                             // B3: drains all sc1 stores
        if (tid == 0)
            __hip_atomic_fetch_add(flg + FLG_OFF(l, t) + ((c >> 4) << 4), 1u,
                                   __ATOMIC_RELAXED, __HIP_MEMORY_SCOPE_AGENT);
    }
}

// ---------------------------------------------------------------------------
__global__ __launch_bounds__(256) void ln_kernel(float* __restrict__ out,
                                                 const float* __restrict__ g,
                                                 const float* __restrict__ bvec) {
    float* p = out + (size_t)blockIdx.x * 768;
    int tid = threadIdx.x;
    float v0 = p[tid], v1 = p[tid + 256], v2 = p[tid + 512];
    float s = v0 + v1 + v2;
    float q = v0 * v0 + v1 * v1 + v2 * v2;
    for (int off = 32; off > 0; off >>= 1) {
        s += __shfl_down(s, off);
        q += __shfl_down(q, off);
    }
    __shared__ float ss[4], qq[4];
    __shared__ float mu_s, rs_s;
    int w = tid >> 6;
    if ((tid & 63) == 0) { ss[w] = s; qq[w] = q; }
    __syncthreads();
    if (tid == 0) {
        float S = ss[0] + ss[1] + ss[2] + ss[3];
        float Q = qq[0] + qq[1] + qq[2] + qq[3];
        float mu = S * (1.f / 768.f);
        float var = Q * (1.f / 768.f) - mu * mu;
        mu_s = mu;
        rs_s = rsqrtf(var + 1e-5f);
    }
    __syncthreads();
    float mu = mu_s, rs = rs_s;
    p[tid]       = (v0 - mu) * rs * g[tid]       + bvec[tid];
    p[tid + 256] = (v1 - mu) * rs * g[tid + 256] + bvec[tid + 256];
    p[tid + 512] = (v2 - mu) * rs * g[tid + 512] + bvec[tid + 512];
}

// ---------------------------------------------------------------------------
extern "C" void kernel_launch(void* const* d_in, const int* in_sizes, int n_in,
                              void* d_out, int out_size, void* d_ws, size_t ws_size,
                              hipStream_t stream) {
    (void)in_sizes; (void)n_in; (void)out_size; (void)ws_size;
    const float* x     = (const float*)d_in[0];
    const float* h0    = (const float*)d_in[1];
    const float* c0    = (const float*)d_in[2];
    const float* W_in  = (const float*)d_in[3];
    const float* b_in  = (const float*)d_in[4];
    const float* W_ih  = (const float*)d_in[5];
    const float* W_hh  = (const float*)d_in[6];
    const float* b_ih  = (const float*)d_in[7];
    const float* b_hh  = (const float*)d_in[8];
    const float* W_out = (const float*)d_in[9];
    const float* b_out = (const float*)d_in[10];
    const float* ln_g  = (const float*)d_in[11];
    const float* ln_b  = (const float*)d_in[12];

    float* out   = (float*)d_out;
    short* h_all = (short*)d_ws;
    short* xp    = h_all + HALL_ELEMS;
    unsigned* flg = (unsigned*)(xp + XP_ELEMS);

    init_kernel<<<1024, 256, 0, stream>>>(h_all, flg, h0);
    gemm_xp<<<dim3(256, 4), 256, 0, stream>>>(x, W_in, b_in, xp);
    lstm_pipeline<<<256, 512, 0, stream>>>(xp, h_all, flg, W_ih, W_hh,
                                           b_ih, b_hh, c0, out);
    gemm_out<<<dim3(256, 6), 256, 0, stream>>>(xp, W_out, b_out, out);
    ln_kernel<<<32768, 256, 0, stream>>>(out, ln_g, ln_b);
}